// Round 4
// baseline (492.372 us; speedup 1.0000x reference)
//
#include <hip/hip_runtime.h>

// 2-layer LSTM, B=1024 T=512 D=1 H=64. 256 blocks x 256 threads (4 waves).
// Each block: 4 batches as TWO independent groups (G0=b0-1, G1=b2-3), each an
// independent recurrence interleaved in the SAME wave -> each group's
// LDS/MFMA/trans chain latency is hidden by the other group's instructions.
// Weights (registers) shared between groups.
// Row-dup trick: A row r = h[r&1] -> C rows give batch r&1, so EVERY lane holds
// both batches of both layer-chains in acc regs 0-1 -> selection is cndmask,
// zero shuffles, 1 lstm_point per lane per group (layer=quad>>1, batch=quad&1).
// LDS H layout (per group, 1024B): L*512 + par*256 + b*128 + chunk(16B)*16,
// chunks XOR-swizzled by key=quad=(L<<1)|b. All LDS traffic <=2-way (free).
// Peeled t=0 / t=512; steady loop t=1..511 branch-free, 1 barrier per step.

typedef _Float16 f16x8 __attribute__((ext_vector_type(8)));
typedef float f32x4 __attribute__((ext_vector_type(4)));

#define TSTEPS 512
#define L2E 1.44269504088896340736f

__device__ __forceinline__ float lstm_point(float ai, float af, float ag, float ao,
                                            float& c) {
    // ai,af,ao pre-scaled by -log2e ; ag by +2log2e
    const float p  = __builtin_amdgcn_exp2f(ai);   // e^-i
    const float s_ = __builtin_amdgcn_exp2f(af);   // e^-f
    const float r_ = __builtin_amdgcn_exp2f(ag);   // e^2g
    const float v  = __builtin_amdgcn_exp2f(ao);   // e^-o
    const float m1 = (1.f + p) * (1.f + r_);
    const float R  = __builtin_amdgcn_rcpf(m1 * (1.f + s_));
    const float f  = m1 * R;                       // sigmoid(f)
    const float ig = (r_ - 1.f) * ((1.f + s_) * R);// sigmoid(i)*tanh(g)
    const float cc = __builtin_fmaf(f, c, ig);
    c = cc;
    const float w  = __builtin_amdgcn_exp2f(cc * (2.f * L2E));
    return (w - 1.f) * __builtin_amdgcn_rcpf((1.f + v) * (1.f + w));
}

__global__ __launch_bounds__(256, 1) void lstm2_kernel(
    const float* __restrict__ x,
    const float* __restrict__ W_ih0, const float* __restrict__ W_hh0,
    const float* __restrict__ b_ih0, const float* __restrict__ b_hh0,
    const float* __restrict__ W_ih1, const float* __restrict__ W_hh1,
    const float* __restrict__ b_ih1, const float* __restrict__ b_hh1,
    const float* __restrict__ W_fc,  const float* __restrict__ b_fc,
    float* __restrict__ out)
{
    // H[G]: 512 f16 = 1024B per group. Byte layout inside a group:
    //   L*512 + par*256 + b*128 + swz_chunk*16 + (unit&7)*2
    __shared__ alignas(16) _Float16 H[2][512];
    __shared__ alignas(16) float    xl[2][64][4];   // [buf][step][batch]

    const int tid  = (int)threadIdx.x;
    const int lane = tid & 63;
    const int w    = tid >> 6;          // wave: units w*16..w*16+15
    const int c    = lane & 15;
    const int quad = lane >> 4;
    const int L    = quad >> 1;         // lane's point: layer
    const int bq   = quad & 1;          //               batch within group
    const int j    = (w << 4) | c;     //                hidden unit
    const int b0   = (int)blockIdx.x * 4;
    const int cb   = c & 1;             // batch held in this lane's A-row

    // byte offsets inside one group's 1024B H block (add par*256 at use)
    const int offA0 = cb * 128 + ((quad ^ cb) & 7) * 16;                 // h0 (L=0)
    const int offA2 = 512 + cb * 128 + ((quad ^ (2 | cb)) & 7) * 16;     // h1 (L=1)
    const int offW  = L * 512 + bq * 128
                    + (((j >> 3) ^ quad) & 7) * 16 + (j & 7) * 2;

    // ---- per-lane weight fragments (shared by both groups) ----
    float biasc0[4], wih0c[4];
    f32x4 cini1[4];
    f16x8 bf0[4][2];              // W_hh0, K=64
    f16x8 bf1[4][4];              // [W_ih1 | W_hh1], K=128

#pragma unroll
    for (int g = 0; g < 4; ++g) {
        const int n = j + 64 * g;
        const float sg = (g == 2) ? (2.0f * L2E) : (-L2E);
        biasc0[g] = sg * (b_ih0[n] + b_hh0[n]);
        wih0c[g]  = sg * W_ih0[n];                 // D == 1
        const float bb1 = sg * (b_ih1[n] + b_hh1[n]);
        cini1[g][0] = bb1; cini1[g][1] = bb1; cini1[g][2] = bb1; cini1[g][3] = bb1;
#pragma unroll
        for (int kb = 0; kb < 2; ++kb) {
            const float* p = W_hh0 + n * 64 + kb * 32 + quad * 8;
#pragma unroll
            for (int q = 0; q < 8; ++q) bf0[g][kb][q] = (_Float16)(p[q] * sg);
        }
#pragma unroll
        for (int kb = 0; kb < 4; ++kb) {
            const int kk = kb * 32 + quad * 8;
            const float* p = (kk < 64) ? (W_ih1 + n * 64 + kk)
                                       : (W_hh1 + n * 64 + (kk - 64));
#pragma unroll
            for (int q = 0; q < 8; ++q) bf1[g][kb][q] = (_Float16)(p[q] * sg);
        }
    }

    // zero-init H (h1 parity-1 must be 0 at t=1; garbage rows never read) + x chunk 0
    for (int i = tid; i < 1024; i += 256) ((_Float16*)H)[i] = (_Float16)0.f;
    {
        const int m = tid >> 6, i = tid & 63;      // coalesced: 64 consecutive floats
        xl[0][i][m] = x[(b0 + m) * TSTEPS + i];
    }
    __syncthreads();

    float cst[2] = {0.f, 0.f};

    // ---- peel t=0: h0(0) = lstm(bias + x0*w_ih), no MFMA; write par 0 ----
#pragma unroll
    for (int G = 0; G < 2; ++G) {
        const float xq = xl[0][0][G * 2 + bq];
        const float g0 = __builtin_fmaf(xq, wih0c[0], biasc0[0]);
        const float g1 = __builtin_fmaf(xq, wih0c[1], biasc0[1]);
        const float g2 = __builtin_fmaf(xq, wih0c[2], biasc0[2]);
        const float g3 = __builtin_fmaf(xq, wih0c[3], biasc0[3]);
        float tmp = cst[G];
        const float hv = lstm_point(g0, g1, g2, g3, tmp);
        if (L == 0) {
            cst[G] = tmp;
            *(_Float16*)((char*)&H[G][0] + offW) = (_Float16)hv;   // offW has L=0, par=0
        }
    }
    __syncthreads();

    // ---- steady loop: t=1..511, all lanes active, 1 barrier/step ----
    for (int t = 1; t < TSTEPS; ++t) {
        if ((t & 63) == 32 && t < 448) {           // stage next x chunk
            const int cn = (t >> 6) + 1;
            const int m = tid >> 6, i = tid & 63;
            xl[cn & 1][i][m] = x[(b0 + m) * TSTEPS + cn * 64 + i];
        }
        const int pr   = (t + 1) & 1;   // h0(t-1) read par; h1(t-1) write par
        const int pr1  = t & 1;         // h1(t-2) read par; h0(t) write par
        const int parW = L ? pr : pr1;

        f16x8 a0[2], a1[2], a2[2], a3[2];
        float xv0[2], xv1[2];
#pragma unroll
        for (int G = 0; G < 2; ++G) {
            const char* HG = (const char*)&H[G][0];
            a0[G] = *(const f16x8*)(HG + pr * 256 + offA0);
            a1[G] = *(const f16x8*)(HG + pr * 256 + offA0 + 64);
            a2[G] = *(const f16x8*)(HG + pr1 * 256 + offA2);
            a3[G] = *(const f16x8*)(HG + pr1 * 256 + offA2 + 64);
            const float* xp = &xl[(t >> 6) & 1][t & 63][G * 2];
            xv0[G] = xp[0]; xv1[G] = xp[1];
        }

        float hv[2];
#pragma unroll
        for (int G = 0; G < 2; ++G) {
            float gate[4];
#pragma unroll
            for (int g = 0; g < 4; ++g) {
                f32x4 ini;
                ini[0] = ini[2] = __builtin_fmaf(xv0[G], wih0c[g], biasc0[g]);
                ini[1] = ini[3] = __builtin_fmaf(xv1[G], wih0c[g], biasc0[g]);
                // layer0, step t (2-chain)
                f32x4 A = __builtin_amdgcn_mfma_f32_16x16x32_f16(a0[G], bf0[g][0], ini, 0, 0, 0);
                A = __builtin_amdgcn_mfma_f32_16x16x32_f16(a1[G], bf0[g][1], A, 0, 0, 0);
                // layer1, step t-1 (4-chain; shares a0,a1 = h0(t-1))
                f32x4 Bq = __builtin_amdgcn_mfma_f32_16x16x32_f16(a0[G], bf1[g][0], cini1[g], 0, 0, 0);
                Bq = __builtin_amdgcn_mfma_f32_16x16x32_f16(a1[G], bf1[g][1], Bq, 0, 0, 0);
                Bq = __builtin_amdgcn_mfma_f32_16x16x32_f16(a2[G], bf1[g][2], Bq, 0, 0, 0);
                Bq = __builtin_amdgcn_mfma_f32_16x16x32_f16(a3[G], bf1[g][3], Bq, 0, 0, 0);
                // every lane: all 4 (L,b) results live in regs 0-1
                const float lo = bq ? A[1]  : A[0];
                const float hi = bq ? Bq[1] : Bq[0];
                gate[g] = L ? hi : lo;
            }
            hv[G] = lstm_point(gate[0], gate[1], gate[2], gate[3], cst[G]);
        }
#pragma unroll
        for (int G = 0; G < 2; ++G)
            *(_Float16*)((char*)&H[G][0] + parW * 256 + offW) = (_Float16)hv[G];
        __syncthreads();
    }

    // ---- peel t=512: h1(511) only (pr=1, pr1=0); all lanes compute, L1 writes ----
#pragma unroll
    for (int G = 0; G < 2; ++G) {
        const char* HG = (const char*)&H[G][0];
        const f16x8 a0 = *(const f16x8*)(HG + 256 + offA0);
        const f16x8 a1 = *(const f16x8*)(HG + 256 + offA0 + 64);
        const f16x8 a2 = *(const f16x8*)(HG + offA2);
        const f16x8 a3 = *(const f16x8*)(HG + offA2 + 64);
        float gate[4];
#pragma unroll
        for (int g = 0; g < 4; ++g) {
            f32x4 Bq = __builtin_amdgcn_mfma_f32_16x16x32_f16(a0, bf1[g][0], cini1[g], 0, 0, 0);
            Bq = __builtin_amdgcn_mfma_f32_16x16x32_f16(a1, bf1[g][1], Bq, 0, 0, 0);
            Bq = __builtin_amdgcn_mfma_f32_16x16x32_f16(a2, bf1[g][2], Bq, 0, 0, 0);
            Bq = __builtin_amdgcn_mfma_f32_16x16x32_f16(a3, bf1[g][3], Bq, 0, 0, 0);
            gate[g] = bq ? Bq[1] : Bq[0];
        }
        float tmp = cst[G];
        const float hv = lstm_point(gate[0], gate[1], gate[2], gate[3], tmp);
        if (L == 1) {
            // h1(511) -> L=1, par=1 slot: offW already has L*512; add par*256
            *(_Float16*)((char*)&H[G][0] + 256 + offW) = (_Float16)hv;
        }
    }
    __syncthreads();

    // ---- epilogue: h0(511) at [L=0,par=1], h1(511) at [L=1,par=1] ----
    if (tid < 8) {
        const int which = tid >> 2, idx = tid & 3;
        const int G = idx >> 1, b = idx & 1;
        const int key = (which << 1) | b;
        const char* hb = (const char*)H + G * 1024 + which * 512 + 256 + b * 128;
        float s = b_fc[0];
        for (int jj = 0; jj < 64; ++jj) {
            const int off = (((jj >> 3) ^ key) & 7) * 16 + (jj & 7) * 2;
            s += (float)*(const _Float16*)(hb + off) * W_fc[jj];
        }
        out[which * 1024 + b0 + G * 2 + b] = s;
    }
}

extern "C" void kernel_launch(void* const* d_in, const int* in_sizes, int n_in,
                              void* d_out, int out_size, void* d_ws, size_t ws_size,
                              hipStream_t stream) {
    (void)in_sizes; (void)n_in; (void)d_ws; (void)ws_size; (void)out_size;
    lstm2_kernel<<<256, 256, 0, stream>>>(
        (const float*)d_in[0],
        (const float*)d_in[1], (const float*)d_in[2],
        (const float*)d_in[3], (const float*)d_in[4],
        (const float*)d_in[5], (const float*)d_in[6],
        (const float*)d_in[7], (const float*)d_in[8],
        (const float*)d_in[9], (const float*)d_in[10],
        (float*)d_out);
}

// Round 5
// 350.629 us; speedup vs baseline: 1.4043x; 1.4043x over previous
//
#include <hip/hip_runtime.h>

// 2-layer LSTM, B=1024 T=512 D=1 H=64. 256 blocks x 256 threads (4 waves), MB=4.
// 4x row-duplication: A row r = h[r&3], so C row 4q+r = batch r for EVERY quad
// -> one 24-MFMA chain-set serves 4 batches x 2 layers, and every lane finds
// all 8 (b,L) gate values in its own accumulator regs. Lane handles 2 points:
// layer L=quad>>1, batches (quad&1)*2+{0,1}, unit j=w*16+(lane&15).
// Zero shuffles; selection = 6 cndmask/gate. 4 ds_read_b128 + 1 x-read /step.
// LDS h layout [L][par][chunk=unit>>3][batch][unit&7] (2B elems): A-reads cover
// a contiguous 256B span (2-way banks = free), no XOR swizzle needed.
// Peeled t=0 / t=512; steady loop t=1..511, 1 barrier per step.

typedef _Float16 f16x8 __attribute__((ext_vector_type(8)));
typedef float f32x4 __attribute__((ext_vector_type(4)));

#define TSTEPS 512
#define L2E 1.44269504088896340736f

__device__ __forceinline__ float lstm_point(float ai, float af, float ag, float ao,
                                            float& c) {
    // ai,af,ao pre-scaled by -log2e ; ag by +2log2e
    const float p  = __builtin_amdgcn_exp2f(ai);   // e^-i
    const float s_ = __builtin_amdgcn_exp2f(af);   // e^-f
    const float r_ = __builtin_amdgcn_exp2f(ag);   // e^2g
    const float v  = __builtin_amdgcn_exp2f(ao);   // e^-o
    const float m1 = (1.f + p) * (1.f + r_);
    const float R  = __builtin_amdgcn_rcpf(m1 * (1.f + s_));
    const float f  = m1 * R;                       // sigmoid(f)
    const float ig = (r_ - 1.f) * ((1.f + s_) * R);// sigmoid(i)*tanh(g)
    const float cc = __builtin_fmaf(f, c, ig);
    c = cc;
    const float w  = __builtin_amdgcn_exp2f(cc * (2.f * L2E));
    return (w - 1.f) * __builtin_amdgcn_rcpf((1.f + v) * (1.f + w));
}

__global__ __launch_bounds__(256, 1) void lstm2_kernel(
    const float* __restrict__ x,
    const float* __restrict__ W_ih0, const float* __restrict__ W_hh0,
    const float* __restrict__ b_ih0, const float* __restrict__ b_hh0,
    const float* __restrict__ W_ih1, const float* __restrict__ W_hh1,
    const float* __restrict__ b_ih1, const float* __restrict__ b_hh1,
    const float* __restrict__ W_fc,  const float* __restrict__ b_fc,
    float* __restrict__ out)
{
    // H bytes: L*1024 + par*512 + chunk*64 + b*16 + (unit&7)*2
    __shared__ alignas(16) _Float16 H[2][2][256];
    __shared__ alignas(16) float    xl[2][64][4];   // [buf][step][batch]

    const int tid  = (int)threadIdx.x;
    const int lane = tid & 63;
    const int w    = tid >> 6;          // wave: units w*16..w*16+15
    const int c    = lane & 15;
    const int quad = lane >> 4;         // 0..3
    const int L    = quad >> 1;         // lane's layer
    const int bh   = quad & 1;          // lane's batch-half (b = 2*bh + r)
    const int j    = (w << 4) | c;      // lane's hidden unit
    const int b0   = (int)blockIdx.x * 4;

    const int rdOff = quad * 64 + (c & 3) * 16;     // A-frag: h[c&3][quad*8+q]
    const int wOff0 = (j >> 3) * 64 + (bh * 2 + 0) * 16 + (j & 7) * 2;
    const int wOff1 = (j >> 3) * 64 + (bh * 2 + 1) * 16 + (j & 7) * 2;

    // ---- per-lane weight fragments ----
    float biasc0[4], wih0c[4];
    f32x4 cini1[4];
    f16x8 bf0[4][2];              // W_hh0, K=64
    f16x8 bf1[4][4];              // [W_ih1 | W_hh1], K=128

#pragma unroll
    for (int g = 0; g < 4; ++g) {
        const int n = j + 64 * g;
        const float sg = (g == 2) ? (2.0f * L2E) : (-L2E);
        biasc0[g] = sg * (b_ih0[n] + b_hh0[n]);
        wih0c[g]  = sg * W_ih0[n];                 // D == 1
        const float bb1 = sg * (b_ih1[n] + b_hh1[n]);
        cini1[g][0] = bb1; cini1[g][1] = bb1; cini1[g][2] = bb1; cini1[g][3] = bb1;
#pragma unroll
        for (int kb = 0; kb < 2; ++kb) {
            const float* p = W_hh0 + n * 64 + kb * 32 + quad * 8;
#pragma unroll
            for (int q = 0; q < 8; ++q) bf0[g][kb][q] = (_Float16)(p[q] * sg);
        }
#pragma unroll
        for (int kb = 0; kb < 4; ++kb) {
            const int kk = kb * 32 + quad * 8;
            const float* p = (kk < 64) ? (W_ih1 + n * 64 + kk)
                                       : (W_hh1 + n * 64 + (kk - 64));
#pragma unroll
            for (int q = 0; q < 8; ++q) bf1[g][kb][q] = (_Float16)(p[q] * sg);
        }
    }

    // zero-init H (h1 par-0/1 must read 0 early) + stage x chunk 0
    for (int i = tid; i < 1024; i += 256) ((_Float16*)H)[i] = (_Float16)0.f;
    {
        const int m = tid >> 6, i = tid & 63;      // coalesced per wave
        xl[0][i][m] = x[(b0 + m) * TSTEPS + i];
    }
    __syncthreads();

    float cst[2] = {0.f, 0.f};   // cell states for (L, 2bh) and (L, 2bh+1)

    // ---- peel t=0: h0(0) = lstm(bias + x0*w_ih); L0 lanes own it ----
    {
        const float xq0 = xl[0][0][bh * 2 + 0];
        const float xq1 = xl[0][0][bh * 2 + 1];
        float tmp0 = 0.f, tmp1 = 0.f;
        const float hv0 = lstm_point(__builtin_fmaf(xq0, wih0c[0], biasc0[0]),
                                     __builtin_fmaf(xq0, wih0c[1], biasc0[1]),
                                     __builtin_fmaf(xq0, wih0c[2], biasc0[2]),
                                     __builtin_fmaf(xq0, wih0c[3], biasc0[3]), tmp0);
        const float hv1 = lstm_point(__builtin_fmaf(xq1, wih0c[0], biasc0[0]),
                                     __builtin_fmaf(xq1, wih0c[1], biasc0[1]),
                                     __builtin_fmaf(xq1, wih0c[2], biasc0[2]),
                                     __builtin_fmaf(xq1, wih0c[3], biasc0[3]), tmp1);
        if (L == 0) {
            cst[0] = tmp0; cst[1] = tmp1;
            char* wb = (char*)H;                    // L=0, par=0
            *(_Float16*)(wb + wOff0) = (_Float16)hv0;
            *(_Float16*)(wb + wOff1) = (_Float16)hv1;
        }
    }
    __syncthreads();

    // ---- steady loop: t=1..511 ----
    for (int t = 1; t < TSTEPS; ++t) {
        if ((t & 63) == 32 && t < 448) {           // stage next x chunk
            const int cn = (t >> 6) + 1;
            const int m = tid >> 6, i = tid & 63;
            xl[cn & 1][i][m] = x[(b0 + m) * TSTEPS + cn * 64 + i];
        }
        const int pr   = (t + 1) & 1;   // h0(t-1) read par; h1(t-1) write par
        const int pr1  = t & 1;         // h1(t-2) read par; h0(t) write par
        const int parW = L ? pr : pr1;

        const char* h0b = (const char*)H + pr * 512;
        const char* h1b = (const char*)H + 1024 + pr1 * 512;
        const f16x8 a0 = *(const f16x8*)(h0b + rdOff);
        const f16x8 a1 = *(const f16x8*)(h0b + rdOff + 256);
        const f16x8 a2 = *(const f16x8*)(h1b + rdOff);
        const f16x8 a3 = *(const f16x8*)(h1b + rdOff + 256);
        const f32x4 xv = *(const f32x4*)&xl[(t >> 6) & 1][t & 63][0];

        float gate0[4], gate1[4];
#pragma unroll
        for (int g = 0; g < 4; ++g) {
            f32x4 ini;
#pragma unroll
            for (int r = 0; r < 4; ++r) ini[r] = __builtin_fmaf(xv[r], wih0c[g], biasc0[g]);
            // layer0, step t (2-chain); C row 4q+r = batch r
            f32x4 A = __builtin_amdgcn_mfma_f32_16x16x32_f16(a0, bf0[g][0], ini, 0, 0, 0);
            A = __builtin_amdgcn_mfma_f32_16x16x32_f16(a1, bf0[g][1], A, 0, 0, 0);
            // layer1, step t-1 (4-chain; shares a0,a1 = h0(t-1))
            f32x4 Bq = __builtin_amdgcn_mfma_f32_16x16x32_f16(a0, bf1[g][0], cini1[g], 0, 0, 0);
            Bq = __builtin_amdgcn_mfma_f32_16x16x32_f16(a1, bf1[g][1], Bq, 0, 0, 0);
            Bq = __builtin_amdgcn_mfma_f32_16x16x32_f16(a2, bf1[g][2], Bq, 0, 0, 0);
            Bq = __builtin_amdgcn_mfma_f32_16x16x32_f16(a3, bf1[g][3], Bq, 0, 0, 0);
            // select this lane's 2 points from its own regs
            const float s0 = bh ? A[2]  : A[0];
            const float s1 = bh ? A[3]  : A[1];
            const float u0 = bh ? Bq[2] : Bq[0];
            const float u1 = bh ? Bq[3] : Bq[1];
            gate0[g] = L ? u0 : s0;
            gate1[g] = L ? u1 : s1;
        }
        const float hv0 = lstm_point(gate0[0], gate0[1], gate0[2], gate0[3], cst[0]);
        const float hv1 = lstm_point(gate1[0], gate1[1], gate1[2], gate1[3], cst[1]);
        char* wb = (char*)H + L * 1024 + parW * 512;
        *(_Float16*)(wb + wOff0) = (_Float16)hv0;
        *(_Float16*)(wb + wOff1) = (_Float16)hv1;
        __syncthreads();
    }

    // ---- peel t=512: h1(511) only (pr=1, pr1=0); L1 lanes write ----
    {
        const char* h0b = (const char*)H + 512;          // h0(511) par1
        const char* h1b = (const char*)H + 1024;         // h1(510) par0
        const f16x8 a0 = *(const f16x8*)(h0b + rdOff);
        const f16x8 a1 = *(const f16x8*)(h0b + rdOff + 256);
        const f16x8 a2 = *(const f16x8*)(h1b + rdOff);
        const f16x8 a3 = *(const f16x8*)(h1b + rdOff + 256);
        float gate0[4], gate1[4];
#pragma unroll
        for (int g = 0; g < 4; ++g) {
            f32x4 Bq = __builtin_amdgcn_mfma_f32_16x16x32_f16(a0, bf1[g][0], cini1[g], 0, 0, 0);
            Bq = __builtin_amdgcn_mfma_f32_16x16x32_f16(a1, bf1[g][1], Bq, 0, 0, 0);
            Bq = __builtin_amdgcn_mfma_f32_16x16x32_f16(a2, bf1[g][2], Bq, 0, 0, 0);
            Bq = __builtin_amdgcn_mfma_f32_16x16x32_f16(a3, bf1[g][3], Bq, 0, 0, 0);
            gate0[g] = bh ? Bq[2] : Bq[0];
            gate1[g] = bh ? Bq[3] : Bq[1];
        }
        float tmp0 = cst[0], tmp1 = cst[1];
        const float hv0 = lstm_point(gate0[0], gate0[1], gate0[2], gate0[3], tmp0);
        const float hv1 = lstm_point(gate1[0], gate1[1], gate1[2], gate1[3], tmp1);
        if (L == 1) {
            char* wb = (char*)H + 1024 + 512;            // L=1, par=1
            *(_Float16*)(wb + wOff0) = (_Float16)hv0;
            *(_Float16*)(wb + wOff1) = (_Float16)hv1;
        }
    }
    __syncthreads();

    // ---- epilogue: h0(511) at [L0,par1], h1(511) at [L1,par1] ----
    if (tid < 8) {
        const int which = tid >> 2, b = tid & 3;
        const char* hb = (const char*)H + which * 1024 + 512;
        float s = b_fc[0];
        for (int jj = 0; jj < 64; ++jj) {
            const int off = (jj >> 3) * 64 + b * 16 + (jj & 7) * 2;
            s += (float)*(const _Float16*)(hb + off) * W_fc[jj];
        }
        out[which * 1024 + b0 + b] = s;
    }
}

extern "C" void kernel_launch(void* const* d_in, const int* in_sizes, int n_in,
                              void* d_out, int out_size, void* d_ws, size_t ws_size,
                              hipStream_t stream) {
    (void)in_sizes; (void)n_in; (void)d_ws; (void)ws_size; (void)out_size;
    lstm2_kernel<<<256, 256, 0, stream>>>(
        (const float*)d_in[0],
        (const float*)d_in[1], (const float*)d_in[2],
        (const float*)d_in[3], (const float*)d_in[4],
        (const float*)d_in[5], (const float*)d_in[6],
        (const float*)d_in[7], (const float*)d_in[8],
        (const float*)d_in[9], (const float*)d_in[10],
        (float*)d_out);
}

// Round 7
// 336.735 us; speedup vs baseline: 1.4622x; 1.0413x over previous
//
#include <hip/hip_runtime.h>

// 2-layer LSTM, B=1024 T=512 D=1 H=64. 256 blocks x 256 threads (4 waves), MB=4.
// R5 structure (4x row-dup, zero shuffles, 2 points/lane) + fixed-cost attack:
//  - t-loop unrolled x2: parities compile-time, LDS addrs = base+imm
//  - ini (x * W_ih0) software-pipelined one step ahead (x staged 32+ steps early)
//  - bias applied post-select via pre-hoisted bsel[] (cini1 eliminated, -12 VGPR)
// R7 fix vs R6: next-pair ini is INI(t+2), not INI(t+3) (off-by-one x-shift).
// LDS H bytes: L*1024 + par*512 + chunk*64 + b*16 + (unit&7)*2  (same as R5)

typedef _Float16 f16x8 __attribute__((ext_vector_type(8)));
typedef float f32x4 __attribute__((ext_vector_type(4)));

#define TSTEPS 512
#define L2E 1.44269504088896340736f

__device__ __forceinline__ float lstm_point(float ai, float af, float ag, float ao,
                                            float& c) {
    // ai,af,ao pre-scaled by -log2e ; ag by +2log2e
    const float p  = __builtin_amdgcn_exp2f(ai);   // e^-i
    const float s_ = __builtin_amdgcn_exp2f(af);   // e^-f
    const float r_ = __builtin_amdgcn_exp2f(ag);   // e^2g
    const float v  = __builtin_amdgcn_exp2f(ao);   // e^-o
    const float m1 = (1.f + p) * (1.f + r_);
    const float R  = __builtin_amdgcn_rcpf(m1 * (1.f + s_));
    const float f  = m1 * R;                       // sigmoid(f)
    const float ig = (r_ - 1.f) * ((1.f + s_) * R);// sigmoid(i)*tanh(g)
    const float cc = __builtin_fmaf(f, c, ig);
    c = cc;
    const float w  = __builtin_amdgcn_exp2f(cc * (2.f * L2E));
    return (w - 1.f) * __builtin_amdgcn_rcpf((1.f + v) * (1.f + w));
}

__global__ __launch_bounds__(256, 1) void lstm2_kernel(
    const float* __restrict__ x,
    const float* __restrict__ W_ih0, const float* __restrict__ W_hh0,
    const float* __restrict__ b_ih0, const float* __restrict__ b_hh0,
    const float* __restrict__ W_ih1, const float* __restrict__ W_hh1,
    const float* __restrict__ b_ih1, const float* __restrict__ b_hh1,
    const float* __restrict__ W_fc,  const float* __restrict__ b_fc,
    float* __restrict__ out)
{
    __shared__ alignas(16) _Float16 H[2][2][256];
    __shared__ alignas(16) float    xl[2][64][4];   // [buf][step][batch]

    const int tid  = (int)threadIdx.x;
    const int lane = tid & 63;
    const int w    = tid >> 6;          // wave: units w*16..w*16+15
    const int c    = lane & 15;
    const int quad = lane >> 4;         // 0..3
    const int L    = quad >> 1;         // lane's layer
    const int bh   = quad & 1;          // lane's batch-half (b = 2*bh + r)
    const int j    = (w << 4) | c;      // lane's hidden unit
    const int b0   = (int)blockIdx.x * 4;

    const int rdOff = quad * 64 + (c & 3) * 16;     // A-frag: h[c&3][quad*8+q]
    const int wOff0 = (j >> 3) * 64 + (bh * 2 + 0) * 16 + (j & 7) * 2;
    const int wOff1 = (j >> 3) * 64 + (bh * 2 + 1) * 16 + (j & 7) * 2;

    // ---- per-lane weight fragments ----
    float biasc0[4], wih0c[4], biasc1[4];
    f16x8 bf0[4][2];              // W_hh0, K=64
    f16x8 bf1[4][4];              // [W_ih1 | W_hh1], K=128

#pragma unroll
    for (int g = 0; g < 4; ++g) {
        const int n = j + 64 * g;
        const float sg = (g == 2) ? (2.0f * L2E) : (-L2E);
        biasc0[g] = sg * (b_ih0[n] + b_hh0[n]);
        wih0c[g]  = sg * W_ih0[n];                 // D == 1
        biasc1[g] = sg * (b_ih1[n] + b_hh1[n]);
#pragma unroll
        for (int kb = 0; kb < 2; ++kb) {
            const float* p = W_hh0 + n * 64 + kb * 32 + quad * 8;
#pragma unroll
            for (int q = 0; q < 8; ++q) bf0[g][kb][q] = (_Float16)(p[q] * sg);
        }
#pragma unroll
        for (int kb = 0; kb < 4; ++kb) {
            const int kk = kb * 32 + quad * 8;
            const float* p = (kk < 64) ? (W_ih1 + n * 64 + kk)
                                       : (W_hh1 + n * 64 + (kk - 64));
#pragma unroll
            for (int q = 0; q < 8; ++q) bf1[g][kb][q] = (_Float16)(p[q] * sg);
        }
    }

    // bias selected once per lane (applied post-select each step)
    float bsel[4];
#pragma unroll
    for (int g = 0; g < 4; ++g) bsel[g] = L ? biasc1[g] : biasc0[g];

    // zero-init H + stage x chunk 0
    for (int i = tid; i < 1024; i += 256) ((_Float16*)H)[i] = (_Float16)0.f;
    {
        const int m = tid >> 6, i = tid & 63;      // coalesced per wave
        xl[0][i][m] = x[(b0 + m) * TSTEPS + i];
    }
    __syncthreads();

    float cst[2] = {0.f, 0.f};   // cell states for (L, 2bh) and (L, 2bh+1)

    // ---- peel t=0: h0(0) = lstm(bias + x0*w_ih); L0 lanes own it ----
    {
        const float xq0 = xl[0][0][bh * 2 + 0];
        const float xq1 = xl[0][0][bh * 2 + 1];
        float tmp0 = 0.f, tmp1 = 0.f;
        const float hv0 = lstm_point(__builtin_fmaf(xq0, wih0c[0], biasc0[0]),
                                     __builtin_fmaf(xq0, wih0c[1], biasc0[1]),
                                     __builtin_fmaf(xq0, wih0c[2], biasc0[2]),
                                     __builtin_fmaf(xq0, wih0c[3], biasc0[3]), tmp0);
        const float hv1 = lstm_point(__builtin_fmaf(xq1, wih0c[0], biasc0[0]),
                                     __builtin_fmaf(xq1, wih0c[1], biasc0[1]),
                                     __builtin_fmaf(xq1, wih0c[2], biasc0[2]),
                                     __builtin_fmaf(xq1, wih0c[3], biasc0[3]), tmp1);
        if (L == 0) {
            cst[0] = tmp0; cst[1] = tmp1;
            char* wb = (char*)H;                    // L=0, par=0
            *(_Float16*)(wb + wOff0) = (_Float16)hv0;
            *(_Float16*)(wb + wOff1) = (_Float16)hv1;
        }
    }
    __syncthreads();

    // precomputed pointers
    char* Hc = (char*)H;
    const char* rdBase = Hc + rdOff;            // + imm selects tile
    // half A (t odd):  pr=0 pr1=1 : h0 @ +0/+256, h1 @ +1536/+1792 ; parW: L?0:1
    // half B (t even): pr=1 pr1=0 : h0 @ +512/+768, h1 @ +1024/+1280 ; parW: L?1:0
    char* wA0 = Hc + (L ? 1024 : 512) + wOff0;
    char* wA1 = Hc + (L ? 1024 : 512) + wOff1;
    char* wB0 = Hc + (L ? 1536 : 0) + wOff0;
    char* wB1 = Hc + (L ? 1536 : 0) + wOff1;

    // one recurrence step given resolved addresses and prefetched ini (x-term)
    const f32x4 zf4 = {0.f, 0.f, 0.f, 0.f};
    auto STEP = [&](int h0imm, int h1imm, char* wp0, char* wp1, const f32x4 (&ini)[4]) {
        const f16x8 a0 = *(const f16x8*)(rdBase + h0imm);
        const f16x8 a1 = *(const f16x8*)(rdBase + h0imm + 256);
        const f16x8 a2 = *(const f16x8*)(rdBase + h1imm);
        const f16x8 a3 = *(const f16x8*)(rdBase + h1imm + 256);
        float gate0[4], gate1[4];
#pragma unroll
        for (int g = 0; g < 4; ++g) {
            // layer0, step t: C row 4q+r = batch r
            f32x4 A = __builtin_amdgcn_mfma_f32_16x16x32_f16(a0, bf0[g][0], ini[g], 0, 0, 0);
            A = __builtin_amdgcn_mfma_f32_16x16x32_f16(a1, bf0[g][1], A, 0, 0, 0);
            // layer1, step t-1 (shares a0,a1 = h0(t-1))
            f32x4 Bq = __builtin_amdgcn_mfma_f32_16x16x32_f16(a0, bf1[g][0], zf4, 0, 0, 0);
            Bq = __builtin_amdgcn_mfma_f32_16x16x32_f16(a1, bf1[g][1], Bq, 0, 0, 0);
            Bq = __builtin_amdgcn_mfma_f32_16x16x32_f16(a2, bf1[g][2], Bq, 0, 0, 0);
            Bq = __builtin_amdgcn_mfma_f32_16x16x32_f16(a3, bf1[g][3], Bq, 0, 0, 0);
            const float s0 = bh ? A[2]  : A[0];
            const float s1 = bh ? A[3]  : A[1];
            const float u0 = bh ? Bq[2] : Bq[0];
            const float u1 = bh ? Bq[3] : Bq[1];
            gate0[g] = (L ? u0 : s0) + bsel[g];
            gate1[g] = (L ? u1 : s1) + bsel[g];
        }
        const float hv0 = lstm_point(gate0[0], gate0[1], gate0[2], gate0[3], cst[0]);
        const float hv1 = lstm_point(gate1[0], gate1[1], gate1[2], gate1[3], cst[1]);
        *(_Float16*)wp0 = (_Float16)hv0;
        *(_Float16*)wp1 = (_Float16)hv1;
    };
    auto INI = [&](int t, f32x4 (&ini)[4]) {
        const f32x4 xv = *(const f32x4*)&xl[(t >> 6) & 1][t & 63][0];
#pragma unroll
        for (int g = 0; g < 4; ++g) {
            ini[g][0] = xv[0] * wih0c[g]; ini[g][1] = xv[1] * wih0c[g];
            ini[g][2] = xv[2] * wih0c[g]; ini[g][3] = xv[3] * wih0c[g];
        }
    };

    f32x4 iniN[4];
    INI(1, iniN);

    // ---- steady pairs: (t, t+1) for t = 1,3,...,509 ----
    for (int t = 1; t <= 509; t += 2) {
        // half A (t odd)
        f32x4 iniB[4];
        INI(t + 1, iniB);                          // independent: fills MFMA shadow
        STEP(0, 1536, wA0, wA1, iniN);
        __syncthreads();

        // half B (t+1 even)
        const int tB = t + 1;
        if ((tB & 63) == 32 && tB < 448) {         // stage next x chunk
            const int cn = (tB >> 6) + 1;
            const int m = tid >> 6, i = tid & 63;
            xl[cn & 1][i][m] = x[(b0 + m) * TSTEPS + cn * 64 + i];
        }
        INI(t + 2, iniN);                          // next pair's half A = step t+2
        STEP(512, 1024, wB0, wB1, iniB);
        __syncthreads();
    }

    // ---- t = 511 (odd, half-A parities), uses iniN = INI(511) ----
    STEP(0, 1536, wA0, wA1, iniN);
    __syncthreads();

    // ---- peel t=512: h1(511) only (pr=1, pr1=0); L1 lanes write ----
    {
        const f16x8 a0 = *(const f16x8*)(rdBase + 512);
        const f16x8 a1 = *(const f16x8*)(rdBase + 768);
        const f16x8 a2 = *(const f16x8*)(rdBase + 1024);
        const f16x8 a3 = *(const f16x8*)(rdBase + 1280);
        float gate0[4], gate1[4];
#pragma unroll
        for (int g = 0; g < 4; ++g) {
            f32x4 Bq = __builtin_amdgcn_mfma_f32_16x16x32_f16(a0, bf1[g][0], zf4, 0, 0, 0);
            Bq = __builtin_amdgcn_mfma_f32_16x16x32_f16(a1, bf1[g][1], Bq, 0, 0, 0);
            Bq = __builtin_amdgcn_mfma_f32_16x16x32_f16(a2, bf1[g][2], Bq, 0, 0, 0);
            Bq = __builtin_amdgcn_mfma_f32_16x16x32_f16(a3, bf1[g][3], Bq, 0, 0, 0);
            gate0[g] = (bh ? Bq[2] : Bq[0]) + bsel[g];
            gate1[g] = (bh ? Bq[3] : Bq[1]) + bsel[g];
        }
        float tmp0 = cst[0], tmp1 = cst[1];
        const float hv0 = lstm_point(gate0[0], gate0[1], gate0[2], gate0[3], tmp0);
        const float hv1 = lstm_point(gate1[0], gate1[1], gate1[2], gate1[3], tmp1);
        if (L == 1) {
            *(_Float16*)(Hc + 1536 + wOff0) = (_Float16)hv0;
            *(_Float16*)(Hc + 1536 + wOff1) = (_Float16)hv1;
        }
    }
    __syncthreads();

    // ---- epilogue: h0(511) at [L0,par1], h1(511) at [L1,par1] ----
    if (tid < 8) {
        const int which = tid >> 2, b = tid & 3;
        const char* hb = (const char*)H + which * 1024 + 512;
        float s = b_fc[0];
        for (int jj = 0; jj < 64; ++jj) {
            const int off = (jj >> 3) * 64 + b * 16 + (jj & 7) * 2;
            s += (float)*(const _Float16*)(hb + off) * W_fc[jj];
        }
        out[which * 1024 + b0 + b] = s;
    }
}

extern "C" void kernel_launch(void* const* d_in, const int* in_sizes, int n_in,
                              void* d_out, int out_size, void* d_ws, size_t ws_size,
                              hipStream_t stream) {
    (void)in_sizes; (void)n_in; (void)d_ws; (void)ws_size; (void)out_size;
    lstm2_kernel<<<256, 256, 0, stream>>>(
        (const float*)d_in[0],
        (const float*)d_in[1], (const float*)d_in[2],
        (const float*)d_in[3], (const float*)d_in[4],
        (const float*)d_in[5], (const float*)d_in[6],
        (const float*)d_in[7], (const float*)d_in[8],
        (const float*)d_in[9], (const float*)d_in[10],
        (float*)d_out);
}